// Round 1
// baseline (548.636 us; speedup 1.0000x reference)
//
#include <hip/hip_runtime.h>

#define BB 4
#define CC 256
#define HH 128
#define WW 128
#define OHH 64
#define OWW 64
#define DD 4096     // OH*OW
#define NPIX 16384  // H*W

__global__ void zero_k(float* __restrict__ p, int n) {
    int i = blockIdx.x * 256 + threadIdx.x;
    if (i < n) p[i] = 0.f;
}

// Fused: qc = Wq@src + bq (never stored), epilogue accumulates
// dot[b,o,ij] = sum_{y,x} qc[b,o,2y+i-1,2x+j-1] * feat[b,o,y,x]
__global__ __launch_bounds__(256) void qcdot_k(const float* __restrict__ src,
                                               const float* __restrict__ feat,
                                               const float* __restrict__ Wq,
                                               const float* __restrict__ bq,
                                               float* __restrict__ dot) {
    __shared__ float Wl[16][65];
    __shared__ float Sl[16][64];
    __shared__ float dot_l[64][9];
    int t = threadIdx.x;
    int bid = blockIdx.x;
    int b    = bid >> 10;        // 1024 blocks per batch
    int rem  = bid & 1023;
    int ob   = rem >> 8;         // 4 o-tiles
    int rem2 = rem & 255;
    int p    = rem2 >> 1;        // row 0..127
    int q0   = (rem2 & 1) << 6;  // 0 or 64
    int o0   = ob << 6;

    for (int i = t; i < 576; i += 256) ((float*)dot_l)[i] = 0.f;

    int to = t >> 4, tp = t & 15;
    float acc[4][4];
#pragma unroll
    for (int u = 0; u < 4; ++u)
#pragma unroll
        for (int uu = 0; uu < 4; ++uu) acc[u][uu] = 0.f;

    const float* srcb = src + (size_t)b * CC * NPIX + p * WW + q0;

    for (int kc = 0; kc < CC; kc += 16) {
        __syncthreads();
#pragma unroll
        for (int r = 0; r < 4; ++r) {
            int idx = r * 256 + t;
            int o_l = idx >> 4, k_l = idx & 15;
            Wl[k_l][o_l] = Wq[(size_t)(o0 + o_l) * CC + kc + k_l];
        }
#pragma unroll
        for (int r = 0; r < 4; ++r) {
            int idx = r * 256 + t;
            int k_l = idx >> 6, q_l = idx & 63;
            Sl[k_l][q_l] = srcb[(size_t)(kc + k_l) * NPIX + q_l];
        }
        __syncthreads();
#pragma unroll
        for (int k = 0; k < 16; ++k) {
            float a[4], bb2[4];
#pragma unroll
            for (int u = 0; u < 4; ++u) a[u] = Wl[k][to * 4 + u];
#pragma unroll
            for (int u = 0; u < 4; ++u) bb2[u] = Sl[k][tp * 4 + u];
#pragma unroll
            for (int u = 0; u < 4; ++u)
#pragma unroll
                for (int uu = 0; uu < 4; ++uu) acc[u][uu] += a[u] * bb2[uu];
        }
    }
    __syncthreads();

    // i-list for this row p: 2y+i-1 = p
    int il[2], yl[2], ni = 0;
    if ((p & 1) == 0) { il[0] = 1; yl[0] = p >> 1; ni = 1; }
    else {
        if (p <= 125) { il[ni] = 0; yl[ni] = (p + 1) >> 1; ni++; }
        il[ni] = 2; yl[ni] = (p - 1) >> 1; ni++;
    }

#pragma unroll
    for (int u = 0; u < 4; ++u) {
        int o = o0 + to * 4 + u;
        float bqv = bq[o];
        const float* fb = feat + ((size_t)b * CC + o) * DD;
#pragma unroll
        for (int uu = 0; uu < 4; ++uu) {
            float qv = acc[u][uu] + bqv;
            int q = q0 + tp * 4 + uu;
            int jl[2], xl[2], nj = 0;
            if ((q & 1) == 0) { jl[0] = 1; xl[0] = q >> 1; nj = 1; }
            else {
                if (q <= 125) { jl[nj] = 0; xl[nj] = (q + 1) >> 1; nj++; }
                jl[nj] = 2; xl[nj] = (q - 1) >> 1; nj++;
            }
            for (int ii = 0; ii < ni; ++ii)
                for (int jj = 0; jj < nj; ++jj) {
                    float f = fb[yl[ii] * OWW + xl[jj]];
                    atomicAdd(&dot_l[to * 4 + u][il[ii] * 3 + jl[jj]], qv * f);
                }
        }
    }
    __syncthreads();
    for (int i = t; i < 576; i += 256) {
        int o_l = i / 9, ij = i % 9;
        atomicAdd(&dot[((size_t)b * CC + o0 + o_l) * 9 + ij], dot_l[o_l][ij]);
    }
}

// v = Wv@feat + bv  -> ws
__global__ __launch_bounds__(256) void vc_k(const float* __restrict__ feat,
                                            const float* __restrict__ Wv,
                                            const float* __restrict__ bv,
                                            float* __restrict__ v) {
    __shared__ float Wl[16][65];
    __shared__ float Sl[16][64];
    int t = threadIdx.x;
    int bid = blockIdx.x;
    int b   = bid >> 8;          // 256 blocks per batch
    int rem = bid & 255;
    int o0  = (rem >> 6) << 6;
    int n0  = (rem & 63) << 6;
    int to = t >> 4, tp = t & 15;
    float acc[4][4];
#pragma unroll
    for (int u = 0; u < 4; ++u)
#pragma unroll
        for (int uu = 0; uu < 4; ++uu) acc[u][uu] = 0.f;

    const float* fb = feat + (size_t)b * CC * DD + n0;
    for (int kc = 0; kc < CC; kc += 16) {
        __syncthreads();
#pragma unroll
        for (int r = 0; r < 4; ++r) {
            int idx = r * 256 + t;
            int o_l = idx >> 4, k_l = idx & 15;
            Wl[k_l][o_l] = Wv[(size_t)(o0 + o_l) * CC + kc + k_l];
        }
#pragma unroll
        for (int r = 0; r < 4; ++r) {
            int idx = r * 256 + t;
            int k_l = idx >> 6, n_l = idx & 63;
            Sl[k_l][n_l] = fb[(size_t)(kc + k_l) * DD + n_l];
        }
        __syncthreads();
#pragma unroll
        for (int k = 0; k < 16; ++k) {
            float a[4], bb2[4];
#pragma unroll
            for (int u = 0; u < 4; ++u) a[u] = Wl[k][to * 4 + u];
#pragma unroll
            for (int u = 0; u < 4; ++u) bb2[u] = Sl[k][tp * 4 + u];
#pragma unroll
            for (int u = 0; u < 4; ++u)
#pragma unroll
                for (int uu = 0; uu < 4; ++uu) acc[u][uu] += a[u] * bb2[uu];
        }
    }
#pragma unroll
    for (int u = 0; u < 4; ++u) {
        int o = o0 + to * 4 + u;
        float bvv = bv[o];
        float4 r;
        r.x = acc[u][0] + bvv; r.y = acc[u][1] + bvv;
        r.z = acc[u][2] + bvv; r.w = acc[u][3] + bvv;
        *reinterpret_cast<float4*>(&v[((size_t)b * CC + o) * DD + n0 + tp * 4]) = r;
    }
}

__global__ void sm_k(const float* __restrict__ dot, float* __restrict__ A) {
    int i = blockIdx.x * 256 + threadIdx.x;
    if (i >= BB * CC) return;
    float s[9];
    float m = -1e30f;
    const float sc = 1.f / 64.f;
#pragma unroll
    for (int k = 0; k < 9; ++k) { s[k] = dot[(size_t)i * 9 + k] * sc; m = fmaxf(m, s[k]); }
    float sum = 0.f;
#pragma unroll
    for (int k = 0; k < 9; ++k) { s[k] = __expf(s[k] - m); sum += s[k]; }
    float inv = 1.f / sum;
#pragma unroll
    for (int k = 0; k < 9; ++k) A[(size_t)i * 9 + k] = s[k] * inv;
}

// out[b,c,h,w] = src * sum_{2y+i=h+1, 2x+j=w+1} A[b,c,3i+j]*v[b,c,y,x]
__global__ __launch_bounds__(256) void out_k(const float* __restrict__ src,
                                             const float* __restrict__ v,
                                             const float* __restrict__ A,
                                             float* __restrict__ out) {
    __shared__ float Al[9];
    int bid = blockIdx.x;
    int bc = bid >> 6;           // b*C + c
    int h0 = (bid & 63) << 1;    // 2 rows per block
    int t = threadIdx.x;
    if (t < 9) Al[t] = A[(size_t)bc * 9 + t];
    __syncthreads();
    int h = h0 + (t >> 7);
    int w = t & 127;
    int hp = h + 1, wp = w + 1;
    int il[2], yl[2], ni = 0;
    if (hp & 1) { il[0] = 1; yl[0] = h >> 1; ni = 1; }
    else {
        int y = hp >> 1;
        if (y <= 63) { il[ni] = 0; yl[ni] = y; ni++; }
        il[ni] = 2; yl[ni] = (hp - 2) >> 1; ni++;
    }
    int jl[2], xl[2], nj = 0;
    if (wp & 1) { jl[0] = 1; xl[0] = w >> 1; nj = 1; }
    else {
        int x = wp >> 1;
        if (x <= 63) { jl[nj] = 0; xl[nj] = x; nj++; }
        jl[nj] = 2; xl[nj] = (wp - 2) >> 1; nj++;
    }
    const float* vb = v + (size_t)bc * DD;
    float sum = 0.f;
    for (int ii = 0; ii < ni; ++ii)
        for (int jj = 0; jj < nj; ++jj)
            sum += Al[il[ii] * 3 + jl[jj]] * vb[yl[ii] * OWW + xl[jj]];
    size_t idx = (size_t)bc * NPIX + (size_t)h * WW + w;
    out[idx] = sum * src[idx];
}

extern "C" void kernel_launch(void* const* d_in, const int* in_sizes, int n_in,
                              void* d_out, int out_size, void* d_ws, size_t ws_size,
                              hipStream_t stream) {
    const float* feat = (const float*)d_in[0];
    const float* src  = (const float*)d_in[1];
    const float* Wq   = (const float*)d_in[2];
    const float* bq   = (const float*)d_in[3];
    const float* Wv   = (const float*)d_in[4];
    const float* bv   = (const float*)d_in[5];
    float* out = (float*)d_out;

    float* v   = (float*)d_ws;                       // 4*256*4096
    float* dot = v + (size_t)BB * CC * DD;           // 4*256*9
    float* A   = dot + (size_t)BB * CC * 9;          // 4*256*9

    zero_k<<<(BB * CC * 9 + 255) / 256, 256, 0, stream>>>(dot, BB * CC * 9);
    qcdot_k<<<BB * 1024, 256, 0, stream>>>(src, feat, Wq, bq, dot);
    vc_k<<<BB * 256, 256, 0, stream>>>(feat, Wv, bv, v);
    sm_k<<<(BB * CC + 255) / 256, 256, 0, stream>>>(dot, A);
    out_k<<<BB * CC * (HH / 2), 256, 0, stream>>>(src, v, A, out);
}

// Round 2
// 395.704 us; speedup vs baseline: 1.3865x; 1.3865x over previous
//
#include <hip/hip_runtime.h>

typedef _Float16 f16;
typedef _Float16 f16x4 __attribute__((ext_vector_type(4)));
typedef _Float16 f16x8 __attribute__((ext_vector_type(8)));
typedef float f32x4 __attribute__((ext_vector_type(4)));

#define BB 4
#define CC 256
#define HH 128
#define WW 128
#define OWW 64
#define DD 4096     // 64*64
#define NPIX 16384  // 128*128

__global__ void zero_k(float* __restrict__ p, int n) {
    int i = blockIdx.x * 256 + threadIdx.x;
    if (i < n) p[i] = 0.f;
}

// Fused qc = Wq@src + bq (f16 MFMA, never stored) with dot-epilogue:
// dot[b,o,3i+j] += sum qc[b,o,h,w]*feat[b,o,y,x] over the fold mapping.
// Block: all 256 o  x  64 px (half of row h). 4 waves, wave-tile 64o x 64px.
__global__ __launch_bounds__(256) void qcdot_k(const float* __restrict__ src,
                                               const float* __restrict__ feat,
                                               const float* __restrict__ Wq,
                                               const float* __restrict__ bq,
                                               float* __restrict__ dot) {
    __shared__ __align__(16) f16 Al[256 * 64];   // [o][c-swz]  32KB
    __shared__ __align__(16) f16 Bl[64 * 64];    // [px][c-swz]  8KB
    __shared__ __align__(16) f16 Fl[256 * 72];   // [o][yi][36] 36KB

    int t = threadIdx.x;
    int bid = blockIdx.x;
    int b = bid >> 8;
    int nt = bid & 255;
    int h = nt >> 1;
    int w0 = (nt & 1) << 6;
    int x0 = w0 >> 1;
    int ybase = h >> 1;

    // ---- stage feat tile: Fl[o][yi][xi], x = x0+xi, y = ybase+yi ----
    {
        const float* fb = feat + (size_t)b * CC * DD;
        for (int it = 0; it < 16; ++it) {
            int tau = it * 256 + t;
            int o = tau >> 4;
            int yi = (tau >> 3) & 1;
            int g4 = tau & 7;
            int y = ybase + yi;
            float4 f = make_float4(0.f, 0.f, 0.f, 0.f);
            if (y < 64) f = *(const float4*)(fb + (size_t)o * DD + y * 64 + x0 + g4 * 4);
            f16x4 hv = {(f16)f.x, (f16)f.y, (f16)f.z, (f16)f.w};
            *(f16x4*)&Fl[o * 72 + yi * 36 + g4 * 4] = hv;
        }
        for (int yi = 0; yi < 2; ++yi) {
            int y = ybase + yi;
            float fv = 0.f;
            if (y < 64 && x0 + 32 < 64) fv = fb[(size_t)t * DD + y * 64 + x0 + 32];
            Fl[t * 72 + yi * 36 + 32] = (f16)fv;
        }
    }

    int wv = t >> 6;
    int lane = t & 63;
    int g = lane >> 4;
    int col = lane & 15;

    f32x4 acc[4][4];
#pragma unroll
    for (int mf = 0; mf < 4; ++mf)
#pragma unroll
        for (int nf = 0; nf < 4; ++nf) acc[mf][nf] = (f32x4){0.f, 0.f, 0.f, 0.f};

    const float* srcb = src + (size_t)b * CC * NPIX + h * WW + w0;

    for (int kk = 0; kk < 4; ++kk) {
        int c0 = kk * 64;
        // stage A = Wq[256][c0..c0+63] -> f16 swizzled
        {
            int orow = t >> 2;
            int cb = (t & 3) << 4;
#pragma unroll
            for (int oo = 0; oo < 4; ++oo) {
                int o = oo * 64 + orow;
                const float* wr = Wq + (size_t)o * CC + c0 + cb;
                float4 f0 = *(const float4*)(wr);
                float4 f1 = *(const float4*)(wr + 4);
                float4 f2 = *(const float4*)(wr + 8);
                float4 f3 = *(const float4*)(wr + 12);
                f16x8 h0 = {(f16)f0.x, (f16)f0.y, (f16)f0.z, (f16)f0.w,
                            (f16)f1.x, (f16)f1.y, (f16)f1.z, (f16)f1.w};
                f16x8 h1 = {(f16)f2.x, (f16)f2.y, (f16)f2.z, (f16)f2.w,
                            (f16)f3.x, (f16)f3.y, (f16)f3.z, (f16)f3.w};
                int Gb = cb >> 3;
                *(f16x8*)&Al[o * 64 + ((Gb ^ (o & 7)) << 3)] = h0;
                *(f16x8*)&Al[o * 64 + (((Gb + 1) ^ (o & 7)) << 3)] = h1;
            }
        }
        // stage B = src[c0..c0+63][w0..w0+63] -> [px][c] f16 swizzled
        {
            int q4 = t & 15;
            int c4 = t >> 4;
            const float* sp = srcb + (size_t)(c0 + c4 * 4) * NPIX + q4 * 4;
            float4 r0 = *(const float4*)(sp);
            float4 r1 = *(const float4*)(sp + NPIX);
            float4 r2 = *(const float4*)(sp + 2 * (size_t)NPIX);
            float4 r3 = *(const float4*)(sp + 3 * (size_t)NPIX);
            int G = c4 >> 1;
            int ho = (c4 & 1) << 2;
#pragma unroll
            for (int p = 0; p < 4; ++p) {
                int px = q4 * 4 + p;
                f16x4 hv = {(f16)(&r0.x)[p], (f16)(&r1.x)[p], (f16)(&r2.x)[p], (f16)(&r3.x)[p]};
                *(f16x4*)&Bl[px * 64 + ((G ^ (px & 7)) << 3) + ho] = hv;
            }
        }
        __syncthreads();
#pragma unroll
        for (int s = 0; s < 2; ++s) {
            f16x8 af[4], bf[4];
            int G = s * 4 + g;
#pragma unroll
            for (int mf = 0; mf < 4; ++mf) {
                int orow = wv * 64 + mf * 16 + col;
                af[mf] = *(const f16x8*)&Al[orow * 64 + ((G ^ (orow & 7)) << 3)];
            }
#pragma unroll
            for (int nf = 0; nf < 4; ++nf) {
                int px = nf * 16 + col;
                bf[nf] = *(const f16x8*)&Bl[px * 64 + ((G ^ (px & 7)) << 3)];
            }
#pragma unroll
            for (int mf = 0; mf < 4; ++mf)
#pragma unroll
                for (int nf = 0; nf < 4; ++nf)
                    acc[mf][nf] = __builtin_amdgcn_mfma_f32_16x16x32_f16(af[mf], bf[nf], acc[mf][nf], 0, 0, 0);
        }
        __syncthreads();
    }

    // ---- epilogue: bin into dot[o][3i+j] ----
    int ni;
    int ivals[2], yis[2];
    if ((h & 1) == 0) { ni = 1; ivals[0] = 1; yis[0] = 0; }
    else {
        ivals[0] = 2; yis[0] = 0; ni = 1;
        if (h <= 125) { ivals[1] = 0; yis[1] = 1; ni = 2; }
    }

    for (int mf = 0; mf < 4; ++mf) {
        float bins[4][2][3];
#pragma unroll
        for (int r = 0; r < 4; ++r)
#pragma unroll
            for (int ii = 0; ii < 2; ++ii)
#pragma unroll
                for (int j = 0; j < 3; ++j) bins[r][ii][j] = 0.f;
        int obase = wv * 64 + mf * 16 + g * 4;
#pragma unroll
        for (int nf = 0; nf < 4; ++nf) {
            int wl = w0 + nf * 16 + col;
#pragma unroll
            for (int r = 0; r < 4; ++r) {
                int o = obase + r;
                float qv = acc[mf][nf][r] + bq[o];
#pragma unroll
                for (int ii = 0; ii < 2; ++ii) {
                    if (ii < ni) {
                        const f16* fro = &Fl[o * 72 + yis[ii] * 36];
                        if ((wl & 1) == 0) {
                            bins[r][ii][1] += qv * (float)fro[(wl - w0) >> 1];
                        } else {
                            bins[r][ii][2] += qv * (float)fro[(wl - 1 - w0) >> 1];
                            if (wl <= 125) bins[r][ii][0] += qv * (float)fro[(wl + 1 - w0) >> 1];
                        }
                    }
                }
            }
        }
        // butterfly reduce over the 16 lanes of each column group
#pragma unroll
        for (int m = 1; m <= 8; m <<= 1)
#pragma unroll
            for (int r = 0; r < 4; ++r)
                for (int ii = 0; ii < ni; ++ii)
#pragma unroll
                    for (int j = 0; j < 3; ++j)
                        bins[r][ii][j] += __shfl_xor(bins[r][ii][j], m, 64);
        if (col == 0) {
            for (int r = 0; r < 4; ++r) {
                int o = obase + r;
                float* dp = dot + ((size_t)b * CC + o) * 9;
                for (int ii = 0; ii < ni; ++ii) {
                    int ib = ivals[ii] * 3;
                    atomicAdd(dp + ib + 0, bins[r][ii][0]);
                    atomicAdd(dp + ib + 1, bins[r][ii][1]);
                    atomicAdd(dp + ib + 2, bins[r][ii][2]);
                }
            }
        }
    }
}

// v = Wv@feat + bv (f16 MFMA). Block: 128 o x 128 d, waves 2x2 (64x64).
__global__ __launch_bounds__(256) void vc_k(const float* __restrict__ feat,
                                            const float* __restrict__ Wv,
                                            const float* __restrict__ bv,
                                            float* __restrict__ v) {
    __shared__ __align__(16) f16 Al[128 * 64];
    __shared__ __align__(16) f16 Bl[128 * 64];
    int t = threadIdx.x;
    int bid = blockIdx.x;
    int b = bid >> 6;
    int rest = bid & 63;
    int o0 = (rest >> 5) * 128;
    int d0 = (rest & 31) * 128;

    int wv = t >> 6;
    int wm = wv >> 1, wn = wv & 1;
    int lane = t & 63;
    int g = lane >> 4;
    int col = lane & 15;

    f32x4 acc[4][4];
#pragma unroll
    for (int mf = 0; mf < 4; ++mf)
#pragma unroll
        for (int nf = 0; nf < 4; ++nf) acc[mf][nf] = (f32x4){0.f, 0.f, 0.f, 0.f};

    const float* featb = feat + (size_t)b * CC * DD + d0;

    for (int kk = 0; kk < 4; ++kk) {
        int c0 = kk * 64;
        {
            int orow = t >> 2;
            int cb = (t & 3) << 4;
#pragma unroll
            for (int oo = 0; oo < 2; ++oo) {
                int o = oo * 64 + orow;
                const float* wr = Wv + (size_t)(o0 + o) * CC + c0 + cb;
                float4 f0 = *(const float4*)(wr);
                float4 f1 = *(const float4*)(wr + 4);
                float4 f2 = *(const float4*)(wr + 8);
                float4 f3 = *(const float4*)(wr + 12);
                f16x8 h0 = {(f16)f0.x, (f16)f0.y, (f16)f0.z, (f16)f0.w,
                            (f16)f1.x, (f16)f1.y, (f16)f1.z, (f16)f1.w};
                f16x8 h1 = {(f16)f2.x, (f16)f2.y, (f16)f2.z, (f16)f2.w,
                            (f16)f3.x, (f16)f3.y, (f16)f3.z, (f16)f3.w};
                int Gb = cb >> 3;
                *(f16x8*)&Al[o * 64 + ((Gb ^ (o & 7)) << 3)] = h0;
                *(f16x8*)&Al[o * 64 + (((Gb + 1) ^ (o & 7)) << 3)] = h1;
            }
        }
        {
            int q4 = t & 31;
            int oc = t >> 5;
            const float* fp = featb + (size_t)(c0 + oc * 8) * DD + q4 * 4;
            float4 rr[8];
#pragma unroll
            for (int r = 0; r < 8; ++r) rr[r] = *(const float4*)(fp + (size_t)r * DD);
#pragma unroll
            for (int p = 0; p < 4; ++p) {
                int d = q4 * 4 + p;
                f16x8 hv = {(f16)(&rr[0].x)[p], (f16)(&rr[1].x)[p], (f16)(&rr[2].x)[p],
                            (f16)(&rr[3].x)[p], (f16)(&rr[4].x)[p], (f16)(&rr[5].x)[p],
                            (f16)(&rr[6].x)[p], (f16)(&rr[7].x)[p]};
                *(f16x8*)&Bl[d * 64 + ((oc ^ (d & 7)) << 3)] = hv;
            }
        }
        __syncthreads();
#pragma unroll
        for (int s = 0; s < 2; ++s) {
            f16x8 af[4], bf[4];
            int G = s * 4 + g;
#pragma unroll
            for (int mf = 0; mf < 4; ++mf) {
                int orow = wm * 64 + mf * 16 + col;
                af[mf] = *(const f16x8*)&Al[orow * 64 + ((G ^ (orow & 7)) << 3)];
            }
#pragma unroll
            for (int nf = 0; nf < 4; ++nf) {
                int drow = wn * 64 + nf * 16 + col;
                bf[nf] = *(const f16x8*)&Bl[drow * 64 + ((G ^ (drow & 7)) << 3)];
            }
#pragma unroll
            for (int mf = 0; mf < 4; ++mf)
#pragma unroll
                for (int nf = 0; nf < 4; ++nf)
                    acc[mf][nf] = __builtin_amdgcn_mfma_f32_16x16x32_f16(af[mf], bf[nf], acc[mf][nf], 0, 0, 0);
        }
        __syncthreads();
    }

    float* vb = v + ((size_t)b * CC + o0) * DD + d0;
#pragma unroll
    for (int mf = 0; mf < 4; ++mf)
#pragma unroll
        for (int nf = 0; nf < 4; ++nf) {
#pragma unroll
            for (int r = 0; r < 4; ++r) {
                int o = wm * 64 + mf * 16 + g * 4 + r;
                int d = wn * 64 + nf * 16 + col;
                vb[(size_t)o * DD + d] = acc[mf][nf][r] + bv[o0 + o];
            }
        }
}

__global__ void sm_k(const float* __restrict__ dot, float* __restrict__ A) {
    int i = blockIdx.x * 256 + threadIdx.x;
    if (i >= BB * CC) return;
    float s[9];
    float m = -1e30f;
    const float sc = 1.f / 64.f;
#pragma unroll
    for (int k = 0; k < 9; ++k) { s[k] = dot[(size_t)i * 9 + k] * sc; m = fmaxf(m, s[k]); }
    float sum = 0.f;
#pragma unroll
    for (int k = 0; k < 9; ++k) { s[k] = __expf(s[k] - m); sum += s[k]; }
    float inv = 1.f / sum;
#pragma unroll
    for (int k = 0; k < 9; ++k) A[(size_t)i * 9 + k] = s[k] * inv;
}

__global__ __launch_bounds__(256) void out_k(const float* __restrict__ src,
                                             const float* __restrict__ v,
                                             const float* __restrict__ A,
                                             float* __restrict__ out) {
    __shared__ float Al[9];
    int bid = blockIdx.x;
    int bc = bid >> 6;
    int h0 = (bid & 63) << 1;
    int t = threadIdx.x;
    if (t < 9) Al[t] = A[(size_t)bc * 9 + t];
    __syncthreads();
    int h = h0 + (t >> 7);
    int w = t & 127;
    int hp = h + 1, wp = w + 1;
    int il[2], yl[2], ni = 0;
    if (hp & 1) { il[0] = 1; yl[0] = h >> 1; ni = 1; }
    else {
        int y = hp >> 1;
        if (y <= 63) { il[ni] = 0; yl[ni] = y; ni++; }
        il[ni] = 2; yl[ni] = (hp - 2) >> 1; ni++;
    }
    int jl[2], xl[2], nj = 0;
    if (wp & 1) { jl[0] = 1; xl[0] = w >> 1; nj = 1; }
    else {
        int x = wp >> 1;
        if (x <= 63) { jl[nj] = 0; xl[nj] = x; nj++; }
        jl[nj] = 2; xl[nj] = (wp - 2) >> 1; nj++;
    }
    const float* vb = v + (size_t)bc * DD;
    float sum = 0.f;
    for (int ii = 0; ii < ni; ++ii)
        for (int jj = 0; jj < nj; ++jj)
            sum += Al[il[ii] * 3 + jl[jj]] * vb[yl[ii] * OWW + xl[jj]];
    size_t idx = (size_t)bc * NPIX + (size_t)h * WW + w;
    out[idx] = sum * src[idx];
}

extern "C" void kernel_launch(void* const* d_in, const int* in_sizes, int n_in,
                              void* d_out, int out_size, void* d_ws, size_t ws_size,
                              hipStream_t stream) {
    const float* feat = (const float*)d_in[0];
    const float* src  = (const float*)d_in[1];
    const float* Wq   = (const float*)d_in[2];
    const float* bq   = (const float*)d_in[3];
    const float* Wv   = (const float*)d_in[4];
    const float* bv   = (const float*)d_in[5];
    float* out = (float*)d_out;

    float* v   = (float*)d_ws;                       // 4*256*4096
    float* dotb = v + (size_t)BB * CC * DD;          // 4*256*9
    float* A   = dotb + (size_t)BB * CC * 9;         // 4*256*9

    zero_k<<<(BB * CC * 9 + 255) / 256, 256, 0, stream>>>(dotb, BB * CC * 9);
    qcdot_k<<<BB * 256, 256, 0, stream>>>(src, feat, Wq, bq, dotb);
    vc_k<<<BB * 64, 256, 0, stream>>>(feat, Wv, bv, v);
    sm_k<<<(BB * CC + 255) / 256, 256, 0, stream>>>(dotb, A);
    out_k<<<BB * CC * (HH / 2), 256, 0, stream>>>(src, v, A, out);
}

// Round 3
// 209.901 us; speedup vs baseline: 2.6138x; 1.8852x over previous
//
#include <hip/hip_runtime.h>

typedef _Float16 f16;
typedef _Float16 f16x4 __attribute__((ext_vector_type(4)));
typedef _Float16 f16x8 __attribute__((ext_vector_type(8)));
typedef float f32x4 __attribute__((ext_vector_type(4)));

#define BB 4
#define CC 256
#define HH 128
#define WW 128
#define OWW 64
#define DD 4096     // 64*64
#define NPIX 16384  // 128*128

__global__ void zero_k(float* __restrict__ p, int n) {
    int i = blockIdx.x * 256 + threadIdx.x;
    if (i < n) p[i] = 0.f;
}

__global__ void prep_feat_k(const float* __restrict__ feat, f16* __restrict__ feath) {
    int i = (blockIdx.x * 256 + threadIdx.x) * 8;
    float4 a = *(const float4*)(feat + i);
    float4 b2 = *(const float4*)(feat + i + 4);
    f16x8 h = {(f16)a.x, (f16)a.y, (f16)a.z, (f16)a.w,
               (f16)b2.x, (f16)b2.y, (f16)b2.z, (f16)b2.w};
    *(f16x8*)(feath + i) = h;
}

// wqh[kk][o][swz(G)*8+e] = Wq[o][kk*64+G*8+e]  (pre-swizzled LDS image)
__global__ void prep_wq_k(const float* __restrict__ Wq, f16* __restrict__ wqh) {
    int t = blockIdx.x * 256 + threadIdx.x;   // 0..2047
    int o = t >> 3, G = t & 7;
#pragma unroll
    for (int kk = 0; kk < 4; ++kk) {
        const float* wr = Wq + (size_t)o * CC + kk * 64 + G * 8;
        float4 a = *(const float4*)wr;
        float4 b2 = *(const float4*)(wr + 4);
        f16x8 hv = {(f16)a.x, (f16)a.y, (f16)a.z, (f16)a.w,
                    (f16)b2.x, (f16)b2.y, (f16)b2.z, (f16)b2.w};
        *(f16x8*)&wqh[kk * 16384 + o * 64 + ((G ^ (o & 7)) << 3)] = hv;
    }
}

// Fused qc = Wq@src + bq (f16 MFMA, never stored) with dot-epilogue.
// Swapped operands: C rows = px (64), cols = o. 4 waves, wave o-range 64.
__global__ __launch_bounds__(256) void qcdot_k(const float* __restrict__ src,
                                               const f16* __restrict__ feath,
                                               const f16* __restrict__ wqh,
                                               const float* __restrict__ bq,
                                               float* __restrict__ dot) {
    __shared__ __align__(16) f16 Al[256 * 64];   // Wq [o][c-swz]   32KB
    __shared__ __align__(16) f16 Bl[64 * 64];    // src [px][c-swz]  8KB
    __shared__ __align__(16) f16 Fl[256 * 80];   // feat [o][yi][40] 40KB

    int t = threadIdx.x;
    int bid = blockIdx.x;
    int b = bid >> 8;
    int nt = bid & 255;
    int h = nt >> 1;
    int w0 = (nt & 1) << 6;
    int x0 = w0 >> 1;
    int ybase = h >> 1;

    // ---- stage feat tile from feath (f16): Fl[o][yi][gx*8..] ----
    {
        const f16* fb = feath + (size_t)b * CC * DD;
#pragma unroll
        for (int it = 0; it < 10; ++it) {
            int gi = it * 256 + t;          // 0..2559
            int o = gi / 10;
            int rem = gi - o * 10;
            int yi = rem / 5;
            int gx = rem - yi * 5;
            int y = ybase + yi;
            int x = x0 + gx * 8;
            f16x8 val = {0, 0, 0, 0, 0, 0, 0, 0};
            if (y < 64 && x < 64)
                val = *(const f16x8*)&fb[((size_t)o * 64 + y) * 64 + x];
            *(f16x8*)&Fl[o * 80 + yi * 40 + gx * 8] = val;
        }
    }

    int wv = t >> 6;
    int lane = t & 63;
    int g = lane >> 4;
    int col = lane & 15;

    f32x4 acc[4][4];
#pragma unroll
    for (int mf = 0; mf < 4; ++mf)
#pragma unroll
        for (int nf = 0; nf < 4; ++nf) acc[mf][nf] = (f32x4){0.f, 0.f, 0.f, 0.f};

    const float* srcb = src + (size_t)b * CC * NPIX + h * WW + w0;

    for (int kk = 0; kk < 4; ++kk) {
        int c0 = kk * 64;
        // A-image: linear cooperative copy (pre-swizzled in ws)
        {
            const f16* sA = wqh + kk * 16384;
#pragma unroll
            for (int it = 0; it < 8; ++it) {
                int idx = (it * 256 + t) * 8;
                *(f16x8*)&Al[idx] = *(const f16x8*)&sA[idx];
            }
        }
        // B: src fp32 -> f16 in-register transpose -> [px][c] swizzled
        {
            int q4 = t & 15;
            int c4 = t >> 4;
            const float* sp = srcb + (size_t)(c0 + c4 * 4) * NPIX + q4 * 4;
            float4 r0 = *(const float4*)(sp);
            float4 r1 = *(const float4*)(sp + NPIX);
            float4 r2 = *(const float4*)(sp + 2 * (size_t)NPIX);
            float4 r3 = *(const float4*)(sp + 3 * (size_t)NPIX);
            int G = c4 >> 1;
            int ho = (c4 & 1) << 2;
#pragma unroll
            for (int p = 0; p < 4; ++p) {
                int px = q4 * 4 + p;
                f16x4 hv = {(f16)(&r0.x)[p], (f16)(&r1.x)[p], (f16)(&r2.x)[p], (f16)(&r3.x)[p]};
                *(f16x4*)&Bl[px * 64 + ((G ^ (px & 7)) << 3) + ho] = hv;
            }
        }
        __syncthreads();
#pragma unroll
        for (int s = 0; s < 2; ++s) {
            f16x8 af[4], bf[4];
            int G = s * 4 + g;
#pragma unroll
            for (int mf = 0; mf < 4; ++mf) {
                int px = mf * 16 + col;
                af[mf] = *(const f16x8*)&Bl[px * 64 + ((G ^ (px & 7)) << 3)];
            }
#pragma unroll
            for (int nf = 0; nf < 4; ++nf) {
                int orow = wv * 64 + nf * 16 + col;
                bf[nf] = *(const f16x8*)&Al[orow * 64 + ((G ^ (orow & 7)) << 3)];
            }
#pragma unroll
            for (int mf = 0; mf < 4; ++mf)
#pragma unroll
                for (int nf = 0; nf < 4; ++nf)
                    acc[mf][nf] = __builtin_amdgcn_mfma_f32_16x16x32_f16(af[mf], bf[nf], acc[mf][nf], 0, 0, 0);
        }
        __syncthreads();
    }

    // ---- epilogue: bin into dot[o][3i+j]; all indices compile-time ----
    int ni, ivals[2], yis[2];
    if ((h & 1) == 0) { ni = 1; ivals[0] = 1; yis[0] = 0; ivals[1] = 0; yis[1] = 0; }
    else {
        ivals[0] = 2; yis[0] = 0;
        if (h < 127) { ni = 2; ivals[1] = 0; yis[1] = 1; }
        else         { ni = 1; ivals[1] = 0; yis[1] = 0; }
    }

    float bqv[4];
#pragma unroll
    for (int nf = 0; nf < 4; ++nf) bqv[nf] = bq[wv * 64 + nf * 16 + col];

    float bins[4][2][3];
#pragma unroll
    for (int nf = 0; nf < 4; ++nf)
#pragma unroll
        for (int ii = 0; ii < 2; ++ii)
#pragma unroll
            for (int j = 0; j < 3; ++j) bins[nf][ii][j] = 0.f;

#pragma unroll
    for (int mf = 0; mf < 4; ++mf) {
#pragma unroll
        for (int r = 0; r < 4; ++r) {
            int wl = w0 + mf * 16 + g * 4 + r;       // parity == r&1
            int xiC = (wl - w0) >> 1;
            int xiL = (wl - 1 - w0) >> 1;
            int xiR = (wl + 1 - w0) >> 1;
            bool okR = wl < 127;
#pragma unroll
            for (int nf = 0; nf < 4; ++nf) {
                int ol = wv * 64 + nf * 16 + col;
                float qv = acc[mf][nf][r] + bqv[nf];
                const f16* fo = Fl + ol * 80;
#pragma unroll
                for (int ii = 0; ii < 2; ++ii) {
                    if (ii < ni) {
                        const f16* fr = fo + yis[ii] * 40;
                        if ((r & 1) == 0) {
                            bins[nf][ii][1] += qv * (float)fr[xiC];
                        } else {
                            bins[nf][ii][2] += qv * (float)fr[xiL];
                            if (okR) bins[nf][ii][0] += qv * (float)fr[xiR];
                        }
                    }
                }
            }
        }
    }

    // reduce over the 4 lanes sharing (col): xor 16, 32
#pragma unroll
    for (int m = 16; m <= 32; m <<= 1)
#pragma unroll
        for (int nf = 0; nf < 4; ++nf)
#pragma unroll
            for (int ii = 0; ii < 2; ++ii)
                if (ii == 0 || ni == 2)
#pragma unroll
                    for (int j = 0; j < 3; ++j)
                        bins[nf][ii][j] += __shfl_xor(bins[nf][ii][j], m, 64);

    if (g == 0) {
#pragma unroll
        for (int nf = 0; nf < 4; ++nf) {
            float* dpo = dot + ((size_t)b * CC + wv * 64 + nf * 16 + col) * 9;
#pragma unroll
            for (int ii = 0; ii < 2; ++ii) {
                if (ii < ni) {
                    int ib = ivals[ii] * 3;
                    atomicAdd(dpo + ib + 0, bins[nf][ii][0]);
                    atomicAdd(dpo + ib + 1, bins[nf][ii][1]);
                    atomicAdd(dpo + ib + 2, bins[nf][ii][2]);
                }
            }
        }
    }
}

// v = Wv@feat + bv (f16 MFMA) -> vh (f16). Block: 128 o x 128 d, waves 2x2.
__global__ __launch_bounds__(256) void vc_k(const float* __restrict__ feat,
                                            const float* __restrict__ Wv,
                                            const float* __restrict__ bv,
                                            f16* __restrict__ vh) {
    __shared__ __align__(16) f16 Al[128 * 64];
    __shared__ __align__(16) f16 Bl[128 * 64];
    int t = threadIdx.x;
    int bid = blockIdx.x;
    int b = bid >> 6;
    int rest = bid & 63;
    int o0 = (rest >> 5) * 128;
    int d0 = (rest & 31) * 128;

    int wv = t >> 6;
    int wm = wv >> 1, wn = wv & 1;
    int lane = t & 63;
    int g = lane >> 4;
    int col = lane & 15;

    f32x4 acc[4][4];
#pragma unroll
    for (int mf = 0; mf < 4; ++mf)
#pragma unroll
        for (int nf = 0; nf < 4; ++nf) acc[mf][nf] = (f32x4){0.f, 0.f, 0.f, 0.f};

    const float* featb = feat + (size_t)b * CC * DD + d0;

    for (int kk = 0; kk < 4; ++kk) {
        int c0 = kk * 64;
        {
            int orow = t >> 2;
            int cb = (t & 3) << 4;
#pragma unroll
            for (int oo = 0; oo < 2; ++oo) {
                int o = oo * 64 + orow;
                const float* wr = Wv + (size_t)(o0 + o) * CC + c0 + cb;
                float4 f0 = *(const float4*)(wr);
                float4 f1 = *(const float4*)(wr + 4);
                float4 f2 = *(const float4*)(wr + 8);
                float4 f3 = *(const float4*)(wr + 12);
                f16x8 h0 = {(f16)f0.x, (f16)f0.y, (f16)f0.z, (f16)f0.w,
                            (f16)f1.x, (f16)f1.y, (f16)f1.z, (f16)f1.w};
                f16x8 h1 = {(f16)f2.x, (f16)f2.y, (f16)f2.z, (f16)f2.w,
                            (f16)f3.x, (f16)f3.y, (f16)f3.z, (f16)f3.w};
                int Gb = cb >> 3;
                *(f16x8*)&Al[o * 64 + ((Gb ^ (o & 7)) << 3)] = h0;
                *(f16x8*)&Al[o * 64 + (((Gb + 1) ^ (o & 7)) << 3)] = h1;
            }
        }
        {
            int q4 = t & 31;
            int oc = t >> 5;
            const float* fp = featb + (size_t)(c0 + oc * 8) * DD + q4 * 4;
            float4 rr[8];
#pragma unroll
            for (int r = 0; r < 8; ++r) rr[r] = *(const float4*)(fp + (size_t)r * DD);
#pragma unroll
            for (int p = 0; p < 4; ++p) {
                int d = q4 * 4 + p;
                f16x8 hv = {(f16)(&rr[0].x)[p], (f16)(&rr[1].x)[p], (f16)(&rr[2].x)[p],
                            (f16)(&rr[3].x)[p], (f16)(&rr[4].x)[p], (f16)(&rr[5].x)[p],
                            (f16)(&rr[6].x)[p], (f16)(&rr[7].x)[p]};
                *(f16x8*)&Bl[d * 64 + ((oc ^ (d & 7)) << 3)] = hv;
            }
        }
        __syncthreads();
#pragma unroll
        for (int s = 0; s < 2; ++s) {
            f16x8 af[4], bf[4];
            int G = s * 4 + g;
#pragma unroll
            for (int mf = 0; mf < 4; ++mf) {
                int orow = wm * 64 + mf * 16 + col;
                af[mf] = *(const f16x8*)&Al[orow * 64 + ((G ^ (orow & 7)) << 3)];
            }
#pragma unroll
            for (int nf = 0; nf < 4; ++nf) {
                int drow = wn * 64 + nf * 16 + col;
                bf[nf] = *(const f16x8*)&Bl[drow * 64 + ((G ^ (drow & 7)) << 3)];
            }
#pragma unroll
            for (int mf = 0; mf < 4; ++mf)
#pragma unroll
                for (int nf = 0; nf < 4; ++nf)
                    acc[mf][nf] = __builtin_amdgcn_mfma_f32_16x16x32_f16(af[mf], bf[nf], acc[mf][nf], 0, 0, 0);
        }
        __syncthreads();
    }

    f16* vb = vh + ((size_t)b * CC + o0) * DD + d0;
#pragma unroll
    for (int mf = 0; mf < 4; ++mf)
#pragma unroll
        for (int nf = 0; nf < 4; ++nf) {
#pragma unroll
            for (int r = 0; r < 4; ++r) {
                int o = wm * 64 + mf * 16 + g * 4 + r;
                int d = wn * 64 + nf * 16 + col;
                vb[(size_t)o * DD + d] = (f16)(acc[mf][nf][r] + bv[o0 + o]);
            }
        }
}

__global__ void sm_k(const float* __restrict__ dot, float* __restrict__ A) {
    int i = blockIdx.x * 256 + threadIdx.x;
    if (i >= BB * CC) return;
    float s[9];
    float m = -1e30f;
    const float sc = 1.f / 64.f;
#pragma unroll
    for (int k = 0; k < 9; ++k) { s[k] = dot[(size_t)i * 9 + k] * sc; m = fmaxf(m, s[k]); }
    float sum = 0.f;
#pragma unroll
    for (int k = 0; k < 9; ++k) { s[k] = __expf(s[k] - m); sum += s[k]; }
    float inv = 1.f / sum;
#pragma unroll
    for (int k = 0; k < 9; ++k) A[(size_t)i * 9 + k] = s[k] * inv;
}

__global__ __launch_bounds__(256) void out_k(const float* __restrict__ src,
                                             const f16* __restrict__ vh,
                                             const float* __restrict__ A,
                                             float* __restrict__ out) {
    __shared__ float Al[9];
    int bid = blockIdx.x;
    int bc = bid >> 6;
    int h0 = (bid & 63) << 1;
    int t = threadIdx.x;
    if (t < 9) Al[t] = A[(size_t)bc * 9 + t];
    __syncthreads();
    int h = h0 + (t >> 7);
    int w = t & 127;
    int hp = h + 1, wp = w + 1;
    int il[2], yl[2], ni = 0;
    if (hp & 1) { il[0] = 1; yl[0] = h >> 1; ni = 1; }
    else {
        int y = hp >> 1;
        if (y <= 63) { il[ni] = 0; yl[ni] = y; ni++; }
        il[ni] = 2; yl[ni] = (hp - 2) >> 1; ni++;
    }
    int jl[2], xl[2], nj = 0;
    if (wp & 1) { jl[0] = 1; xl[0] = w >> 1; nj = 1; }
    else {
        int x = wp >> 1;
        if (x <= 63) { jl[nj] = 0; xl[nj] = x; nj++; }
        jl[nj] = 2; xl[nj] = (wp - 2) >> 1; nj++;
    }
    const f16* vb = vh + (size_t)bc * DD;
    float sum = 0.f;
    for (int ii = 0; ii < ni; ++ii)
        for (int jj = 0; jj < nj; ++jj)
            sum += Al[il[ii] * 3 + jl[jj]] * (float)vb[yl[ii] * OWW + xl[jj]];
    size_t idx = (size_t)bc * NPIX + (size_t)h * WW + w;
    out[idx] = sum * src[idx];
}

extern "C" void kernel_launch(void* const* d_in, const int* in_sizes, int n_in,
                              void* d_out, int out_size, void* d_ws, size_t ws_size,
                              hipStream_t stream) {
    const float* feat = (const float*)d_in[0];
    const float* src  = (const float*)d_in[1];
    const float* Wq   = (const float*)d_in[2];
    const float* bq   = (const float*)d_in[3];
    const float* Wv   = (const float*)d_in[4];
    const float* bv   = (const float*)d_in[5];
    float* out = (float*)d_out;

    f16*  vh    = (f16*)d_ws;                               // 4.19M f16
    float* dotb = (float*)(vh + (size_t)BB * CC * DD);      // 9216 f32
    float* A    = dotb + (size_t)BB * CC * 9;               // 9216 f32
    f16*  feath = (f16*)(A + (size_t)BB * CC * 9);          // 4.19M f16
    f16*  wqh   = feath + (size_t)BB * CC * DD + 64;        // 65536 f16

    zero_k<<<(BB * CC * 9 + 255) / 256, 256, 0, stream>>>(dotb, BB * CC * 9);
    prep_feat_k<<<BB * CC * DD / 2048, 256, 0, stream>>>(feat, feath);
    prep_wq_k<<<8, 256, 0, stream>>>(Wq, wqh);
    qcdot_k<<<BB * 256, 256, 0, stream>>>(src, feath, wqh, bq, dotb);
    vc_k<<<BB * 64, 256, 0, stream>>>(feat, Wv, bv, vh);
    sm_k<<<(BB * CC + 255) / 256, 256, 0, stream>>>(dotb, A);
    out_k<<<BB * CC * (HH / 2), 256, 0, stream>>>(src, vh, A, out);
}

// Round 4
// 191.154 us; speedup vs baseline: 2.8701x; 1.0981x over previous
//
#include <hip/hip_runtime.h>

typedef _Float16 f16;
typedef _Float16 f16x2 __attribute__((ext_vector_type(2)));
typedef _Float16 f16x4 __attribute__((ext_vector_type(4)));
typedef _Float16 f16x8 __attribute__((ext_vector_type(8)));
typedef float f32x4 __attribute__((ext_vector_type(4)));

#define BB 4
#define CC 256
#define HH 128
#define WW 128
#define OWW 64
#define DD 4096     // 64*64
#define NPIX 16384  // 128*128

__global__ void zero_k(float* __restrict__ p, int n) {
    int i = blockIdx.x * 256 + threadIdx.x;
    if (i < n) p[i] = 0.f;
}

__global__ void prep_feat_k(const float* __restrict__ feat, f16* __restrict__ feath) {
    int i = (blockIdx.x * 256 + threadIdx.x) * 8;
    float4 a = *(const float4*)(feat + i);
    float4 b2 = *(const float4*)(feat + i + 4);
    f16x8 h = {(f16)a.x, (f16)a.y, (f16)a.z, (f16)a.w,
               (f16)b2.x, (f16)b2.y, (f16)b2.z, (f16)b2.w};
    *(f16x8*)(feath + i) = h;
}

// wqh2[((kk*8+G)*256 + o)*8 + e] = Wq[o][kk*64 + G*8 + e]  (per-lane MFMA frags)
__global__ void prep_wq_k(const float* __restrict__ Wq, f16* __restrict__ wqh2) {
    int t = blockIdx.x * 256 + threadIdx.x;   // 0..2047
    int G = t >> 8, o = t & 255;
#pragma unroll
    for (int kk = 0; kk < 4; ++kk) {
        const float* wr = Wq + (size_t)o * CC + kk * 64 + G * 8;
        float4 a = *(const float4*)wr;
        float4 b2 = *(const float4*)(wr + 4);
        f16x8 hv = {(f16)a.x, (f16)a.y, (f16)a.z, (f16)a.w,
                    (f16)b2.x, (f16)b2.y, (f16)b2.z, (f16)b2.w};
        *(f16x8*)&wqh2[(size_t)(((kk * 8 + G) * 256) + o) * 8] = hv;
    }
}

// Fused qc = Wq@src + bq (f16 MFMA, never stored) with dot-epilogue.
// Block = (b, h-pair, w-half): rows h,h+1 (h even), 64 w. 512 thr, 8 waves.
// Wave wv: rh = wv>>2 (row within pair), o0 = (wv&3)*64.
__global__ __launch_bounds__(512, 3) void qcdot_k(const float* __restrict__ src,
                                                  const f16* __restrict__ feath,
                                                  const f16* __restrict__ wqh2,
                                                  const float* __restrict__ bq,
                                                  float* __restrict__ dot) {
    __shared__ __align__(16) f16 Bl[2][128 * 64];  // src [px][c-swz], dbuf 2x16KB
    __shared__ __align__(16) f16 Fl[512 * 36];     // feat [(o*2+yi)][36]  36.9KB

    int t = threadIdx.x;
    int bid = blockIdx.x;
    int b = bid >> 7;
    int hp = (bid >> 1) & 63;
    int wh = bid & 1;
    int h = hp * 2;
    int w0 = wh * 64;
    int x0 = wh * 32;
    int ybase = hp;

    // ---- B-stage prologue: issue kk=0 loads ----
    const float* srcb = src + (size_t)b * CC * NPIX + h * WW + w0;
    int q4 = t & 15, rh_t = (t >> 4) & 1, c4 = t >> 5;
    const float* sp0 = srcb + (size_t)(c4 * 4) * NPIX + rh_t * WW + q4 * 4;
    float4 rr[4];
#pragma unroll
    for (int r = 0; r < 4; ++r) rr[r] = *(const float4*)(sp0 + (size_t)r * NPIX);

    // ---- stage feat tile: Fl[(o*2+yi)*36 + xi], x = x0+xi, y = ybase+yi ----
    {
        const f16* fb = feath + (size_t)b * CC * DD;
        int o = t >> 1, yi = t & 1;
        int y = ybase + yi;
        const f16* frow = fb + (size_t)o * DD + y * 64 + x0;
        f16* dst = &Fl[(o * 2 + yi) * 36];
        if (y < 64) {
#pragma unroll
            for (int k2 = 0; k2 < 4; ++k2)
                *(f16x8*)&dst[k2 * 8] = *(const f16x8*)&frow[k2 * 8];
            dst[32] = (x0 + 32 < 64) ? frow[32] : (f16)0.f;
        } else {
            f16x8 z = {0, 0, 0, 0, 0, 0, 0, 0};
#pragma unroll
            for (int k2 = 0; k2 < 4; ++k2) *(f16x8*)&dst[k2 * 8] = z;
            dst[32] = (f16)0.f;
        }
    }

    int wv = t >> 6;
    int lane = t & 63;
    int g = lane >> 4;
    int col = lane & 15;
    int rh = wv >> 2;
    int o0 = (wv & 3) * 64;

    f32x4 acc[4][4];
#pragma unroll
    for (int mf = 0; mf < 4; ++mf)
#pragma unroll
        for (int nf = 0; nf < 4; ++nf) acc[mf][nf] = (f32x4){0.f, 0.f, 0.f, 0.f};

    int Gw = c4 >> 1, ho = (c4 & 1) << 2;

#pragma unroll
    for (int kk = 0; kk < 4; ++kk) {
        // 1. write current staged regs -> Bl[kk&1]
#pragma unroll
        for (int p = 0; p < 4; ++p) {
            int px = rh_t * 64 + q4 * 4 + p;
            f16x4 hv = {(f16)(&rr[0].x)[p], (f16)(&rr[1].x)[p],
                        (f16)(&rr[2].x)[p], (f16)(&rr[3].x)[p]};
            *(f16x4*)&Bl[kk & 1][px * 64 + ((Gw ^ (px & 7)) << 3) + ho] = hv;
        }
        // 2. issue next-kk src loads + this-kk Wq frag loads (global, L2-hot)
        float4 nx[4];
        if (kk < 3) {
            const float* spn = srcb + (size_t)((kk + 1) * 64 + c4 * 4) * NPIX + rh_t * WW + q4 * 4;
#pragma unroll
            for (int r = 0; r < 4; ++r) nx[r] = *(const float4*)(spn + (size_t)r * NPIX);
        }
        f16x8 bf[2][4];
#pragma unroll
        for (int s = 0; s < 2; ++s)
#pragma unroll
            for (int nf = 0; nf < 4; ++nf) {
                int o = o0 + nf * 16 + col;
                bf[s][nf] = *(const f16x8*)&wqh2[(size_t)(((kk * 8 + s * 4 + g) * 256) + o) * 8];
            }
        // 3. barrier: Bl[kk&1] now visible
        __syncthreads();
        // 4. MFMA from Bl[kk&1]
#pragma unroll
        for (int s = 0; s < 2; ++s) {
            int G2 = s * 4 + g;
            f16x8 af[4];
#pragma unroll
            for (int mf = 0; mf < 4; ++mf) {
                int px = rh * 64 + mf * 16 + col;
                af[mf] = *(const f16x8*)&Bl[kk & 1][px * 64 + ((G2 ^ (px & 7)) << 3)];
            }
#pragma unroll
            for (int mf = 0; mf < 4; ++mf)
#pragma unroll
                for (int nf = 0; nf < 4; ++nf)
                    acc[mf][nf] = __builtin_amdgcn_mfma_f32_16x16x32_f16(af[mf], bf[s][nf], acc[mf][nf], 0, 0, 0);
        }
        // 5. carry staged regs
#pragma unroll
        for (int r = 0; r < 4; ++r) rr[r] = nx[r];
    }

    // ---- epilogue ----
    // row h+rh: rh=0 (even): i=1 (yi=0). rh=1 (odd): i=2 (yi=0), i=0 (yi=1).
    int i0 = rh ? 2 : 1;
    float bqv[4];
#pragma unroll
    for (int nf = 0; nf < 4; ++nf) bqv[nf] = bq[o0 + nf * 16 + col];

    float bins[4][2][3];
#pragma unroll
    for (int nf = 0; nf < 4; ++nf)
#pragma unroll
        for (int ii = 0; ii < 2; ++ii)
#pragma unroll
            for (int j = 0; j < 3; ++j) bins[nf][ii][j] = 0.f;

#pragma unroll
    for (int mf = 0; mf < 4; ++mf) {
        int X = mf * 8 + g * 2;
#pragma unroll
        for (int ii = 0; ii < 2; ++ii) {
            if (ii == 1 && rh == 0) continue;   // wave-uniform skip
#pragma unroll
            for (int nf = 0; nf < 4; ++nf) {
                int o = o0 + nf * 16 + col;
                const f16* fr = &Fl[(o * 2 + ii) * 36];
                f16x2 lh = *(const f16x2*)&fr[X];
                float lo = (float)lh[0], hi = (float)lh[1];
                float s2 = (float)fr[X + 2];
                float qv0 = acc[mf][nf][0] + bqv[nf];
                float qv1 = acc[mf][nf][1] + bqv[nf];
                float qv2 = acc[mf][nf][2] + bqv[nf];
                float qv3 = acc[mf][nf][3] + bqv[nf];
                bins[nf][ii][1] += qv0 * lo + qv2 * hi;   // j=1 (even w)
                bins[nf][ii][2] += qv1 * lo + qv3 * hi;   // j=2 (odd w, left)
                bins[nf][ii][0] += qv1 * hi + qv3 * s2;   // j=0 (odd w, right)
            }
        }
    }

    // reduce over the 4 lanes sharing col (xor 16, 32)
#pragma unroll
    for (int m = 16; m <= 32; m <<= 1)
#pragma unroll
        for (int nf = 0; nf < 4; ++nf)
#pragma unroll
            for (int ii = 0; ii < 2; ++ii) {
                if (ii == 1 && rh == 0) continue;
#pragma unroll
                for (int j = 0; j < 3; ++j)
                    bins[nf][ii][j] += __shfl_xor(bins[nf][ii][j], m, 64);
            }

    if (g == 0) {
#pragma unroll
        for (int nf = 0; nf < 4; ++nf) {
            int o = o0 + nf * 16 + col;
            float* dpo = dot + ((size_t)b * CC + o) * 9;
            atomicAdd(dpo + i0 * 3 + 0, bins[nf][0][0]);
            atomicAdd(dpo + i0 * 3 + 1, bins[nf][0][1]);
            atomicAdd(dpo + i0 * 3 + 2, bins[nf][0][2]);
            if (rh) {
                atomicAdd(dpo + 0, bins[nf][1][0]);
                atomicAdd(dpo + 1, bins[nf][1][1]);
                atomicAdd(dpo + 2, bins[nf][1][2]);
            }
        }
    }
}

// v = Wv@feat + bv (f16 MFMA) -> vh (f16). Block: 128 o x 128 d, waves 2x2.
__global__ __launch_bounds__(256) void vc_k(const float* __restrict__ feat,
                                            const float* __restrict__ Wv,
                                            const float* __restrict__ bv,
                                            f16* __restrict__ vh) {
    __shared__ __align__(16) f16 Al[128 * 64];
    __shared__ __align__(16) f16 Bl[128 * 64];
    int t = threadIdx.x;
    int bid = blockIdx.x;
    int b = bid >> 6;
    int rest = bid & 63;
    int o0 = (rest >> 5) * 128;
    int d0 = (rest & 31) * 128;

    int wv = t >> 6;
    int wm = wv >> 1, wn = wv & 1;
    int lane = t & 63;
    int g = lane >> 4;
    int col = lane & 15;

    f32x4 acc[4][4];
#pragma unroll
    for (int mf = 0; mf < 4; ++mf)
#pragma unroll
        for (int nf = 0; nf < 4; ++nf) acc[mf][nf] = (f32x4){0.f, 0.f, 0.f, 0.f};

    const float* featb = feat + (size_t)b * CC * DD + d0;

    for (int kk = 0; kk < 4; ++kk) {
        int c0 = kk * 64;
        {
            int orow = t >> 2;
            int cb = (t & 3) << 4;
#pragma unroll
            for (int oo = 0; oo < 2; ++oo) {
                int o = oo * 64 + orow;
                const float* wr = Wv + (size_t)(o0 + o) * CC + c0 + cb;
                float4 f0 = *(const float4*)(wr);
                float4 f1 = *(const float4*)(wr + 4);
                float4 f2 = *(const float4*)(wr + 8);
                float4 f3 = *(const float4*)(wr + 12);
                f16x8 h0 = {(f16)f0.x, (f16)f0.y, (f16)f0.z, (f16)f0.w,
                            (f16)f1.x, (f16)f1.y, (f16)f1.z, (f16)f1.w};
                f16x8 h1 = {(f16)f2.x, (f16)f2.y, (f16)f2.z, (f16)f2.w,
                            (f16)f3.x, (f16)f3.y, (f16)f3.z, (f16)f3.w};
                int Gb = cb >> 3;
                *(f16x8*)&Al[o * 64 + ((Gb ^ (o & 7)) << 3)] = h0;
                *(f16x8*)&Al[o * 64 + (((Gb + 1) ^ (o & 7)) << 3)] = h1;
            }
        }
        {
            int q4b = t & 31;
            int oc = t >> 5;
            const float* fp = featb + (size_t)(c0 + oc * 8) * DD + q4b * 4;
            float4 rr[8];
#pragma unroll
            for (int r = 0; r < 8; ++r) rr[r] = *(const float4*)(fp + (size_t)r * DD);
#pragma unroll
            for (int p = 0; p < 4; ++p) {
                int d = q4b * 4 + p;
                f16x8 hv = {(f16)(&rr[0].x)[p], (f16)(&rr[1].x)[p], (f16)(&rr[2].x)[p],
                            (f16)(&rr[3].x)[p], (f16)(&rr[4].x)[p], (f16)(&rr[5].x)[p],
                            (f16)(&rr[6].x)[p], (f16)(&rr[7].x)[p]};
                *(f16x8*)&Bl[d * 64 + ((oc ^ (d & 7)) << 3)] = hv;
            }
        }
        __syncthreads();
#pragma unroll
        for (int s = 0; s < 2; ++s) {
            f16x8 af[4], bf[4];
            int G = s * 4 + g;
#pragma unroll
            for (int mf = 0; mf < 4; ++mf) {
                int orow = wm * 64 + mf * 16 + col;
                af[mf] = *(const f16x8*)&Al[orow * 64 + ((G ^ (orow & 7)) << 3)];
            }
#pragma unroll
            for (int nf = 0; nf < 4; ++nf) {
                int drow = wn * 64 + nf * 16 + col;
                bf[nf] = *(const f16x8*)&Bl[drow * 64 + ((G ^ (drow & 7)) << 3)];
            }
#pragma unroll
            for (int mf = 0; mf < 4; ++mf)
#pragma unroll
                for (int nf = 0; nf < 4; ++nf)
                    acc[mf][nf] = __builtin_amdgcn_mfma_f32_16x16x32_f16(af[mf], bf[nf], acc[mf][nf], 0, 0, 0);
        }
        __syncthreads();
    }

    f16* vb = vh + ((size_t)b * CC + o0) * DD + d0;
#pragma unroll
    for (int mf = 0; mf < 4; ++mf)
#pragma unroll
        for (int nf = 0; nf < 4; ++nf) {
#pragma unroll
            for (int r = 0; r < 4; ++r) {
                int o = wm * 64 + mf * 16 + g * 4 + r;
                int d = wn * 64 + nf * 16 + col;
                vb[(size_t)o * DD + d] = (f16)(acc[mf][nf][r] + bv[o0 + o]);
            }
        }
}

__global__ void sm_k(const float* __restrict__ dot, float* __restrict__ A) {
    int i = blockIdx.x * 256 + threadIdx.x;
    if (i >= BB * CC) return;
    float s[9];
    float m = -1e30f;
    const float sc = 1.f / 64.f;
#pragma unroll
    for (int k = 0; k < 9; ++k) { s[k] = dot[(size_t)i * 9 + k] * sc; m = fmaxf(m, s[k]); }
    float sum = 0.f;
#pragma unroll
    for (int k = 0; k < 9; ++k) { s[k] = __expf(s[k] - m); sum += s[k]; }
    float inv = 1.f / sum;
#pragma unroll
    for (int k = 0; k < 9; ++k) A[(size_t)i * 9 + k] = s[k] * inv;
}

__global__ __launch_bounds__(256) void out_k(const float* __restrict__ src,
                                             const f16* __restrict__ vh,
                                             const float* __restrict__ A,
                                             float* __restrict__ out) {
    __shared__ float Al[9];
    int bid = blockIdx.x;
    int bc = bid >> 6;
    int h0 = (bid & 63) << 1;
    int t = threadIdx.x;
    if (t < 9) Al[t] = A[(size_t)bc * 9 + t];
    __syncthreads();
    int h = h0 + (t >> 7);
    int w = t & 127;
    int hp = h + 1, wp = w + 1;
    int il[2], yl[2], ni = 0;
    if (hp & 1) { il[0] = 1; yl[0] = h >> 1; ni = 1; }
    else {
        int y = hp >> 1;
        if (y <= 63) { il[ni] = 0; yl[ni] = y; ni++; }
        il[ni] = 2; yl[ni] = (hp - 2) >> 1; ni++;
    }
    int jl[2], xl[2], nj = 0;
    if (wp & 1) { jl[0] = 1; xl[0] = w >> 1; nj = 1; }
    else {
        int x = wp >> 1;
        if (x <= 63) { jl[nj] = 0; xl[nj] = x; nj++; }
        jl[nj] = 2; xl[nj] = (wp - 2) >> 1; nj++;
    }
    const f16* vb = vh + (size_t)bc * DD;
    float sum = 0.f;
    for (int ii = 0; ii < ni; ++ii)
        for (int jj = 0; jj < nj; ++jj)
            sum += Al[il[ii] * 3 + jl[jj]] * (float)vb[yl[ii] * OWW + xl[jj]];
    size_t idx = (size_t)bc * NPIX + (size_t)h * WW + w;
    out[idx] = sum * src[idx];
}

extern "C" void kernel_launch(void* const* d_in, const int* in_sizes, int n_in,
                              void* d_out, int out_size, void* d_ws, size_t ws_size,
                              hipStream_t stream) {
    const float* feat = (const float*)d_in[0];
    const float* src  = (const float*)d_in[1];
    const float* Wq   = (const float*)d_in[2];
    const float* bq   = (const float*)d_in[3];
    const float* Wv   = (const float*)d_in[4];
    const float* bv   = (const float*)d_in[5];
    float* out = (float*)d_out;

    f16*  vh    = (f16*)d_ws;                               // 4*256*4096 f16
    float* dotb = (float*)(vh + (size_t)BB * CC * DD);      // 9216 f32
    float* A    = dotb + (size_t)BB * CC * 9;               // 9216 f32
    f16*  feath = (f16*)(A + (size_t)BB * CC * 9);          // 4*256*4096 f16
    f16*  wqh2  = feath + (size_t)BB * CC * DD + 64;        // 65536 f16

    zero_k<<<(BB * CC * 9 + 255) / 256, 256, 0, stream>>>(dotb, BB * CC * 9);
    prep_feat_k<<<BB * CC * DD / 2048, 256, 0, stream>>>(feat, feath);
    prep_wq_k<<<8, 256, 0, stream>>>(Wq, wqh2);
    qcdot_k<<<BB * 64 * 2, 512, 0, stream>>>(src, feath, wqh2, bq, dotb);
    vc_k<<<BB * 64, 256, 0, stream>>>(feat, Wv, bv, vh);
    sm_k<<<(BB * CC + 255) / 256, 256, 0, stream>>>(dotb, A);
    out_k<<<BB * CC * (HH / 2), 256, 0, stream>>>(src, vh, A, out);
}

// Round 5
// 135.819 us; speedup vs baseline: 4.0395x; 1.4074x over previous
//
#include <hip/hip_runtime.h>

typedef _Float16 f16;
typedef _Float16 f16x2 __attribute__((ext_vector_type(2)));
typedef _Float16 f16x4 __attribute__((ext_vector_type(4)));
typedef _Float16 f16x8 __attribute__((ext_vector_type(8)));
typedef float f32x4 __attribute__((ext_vector_type(4)));

#define BB 4
#define CC 256
#define HH 128
#define WW 128
#define OWW 64
#define DD 4096     // 64*64
#define NPIX 16384  // 128*128

__global__ void zero_k(float* __restrict__ p, int n) {
    int i = blockIdx.x * 256 + threadIdx.x;
    if (i < n) p[i] = 0.f;
}

__global__ void prep_feat_k(const float* __restrict__ feat, f16* __restrict__ feath) {
    int i = (blockIdx.x * 256 + threadIdx.x) * 8;
    float4 a = *(const float4*)(feat + i);
    float4 b2 = *(const float4*)(feat + i + 4);
    f16x8 h = {(f16)a.x, (f16)a.y, (f16)a.z, (f16)a.w,
               (f16)b2.x, (f16)b2.y, (f16)b2.z, (f16)b2.w};
    *(f16x8*)(feath + i) = h;
}

// wqh2[((kk*8+G)*256 + o)*8 + e] = Wq[o][kk*64 + G*8 + e]  (per-lane MFMA frags)
__global__ void prep_wq_k(const float* __restrict__ Wq, f16* __restrict__ wqh2) {
    int t = blockIdx.x * 256 + threadIdx.x;   // 0..2047
    int G = t >> 8, o = t & 255;
#pragma unroll
    for (int kk = 0; kk < 4; ++kk) {
        const float* wr = Wq + (size_t)o * CC + kk * 64 + G * 8;
        float4 a = *(const float4*)wr;
        float4 b2 = *(const float4*)(wr + 4);
        f16x8 hv = {(f16)a.x, (f16)a.y, (f16)a.z, (f16)a.w,
                    (f16)b2.x, (f16)b2.y, (f16)b2.z, (f16)b2.w};
        *(f16x8*)&wqh2[(size_t)(((kk * 8 + G) * 256) + o) * 8] = hv;
    }
}

// Fused qc = Wq@src + bq (f16 MFMA, never stored) with dot-epilogue.
// Block = (b, h-pair, w-half). 512 thr, 8 waves: rh = wv>>2, o0 = (wv&3)*64.
// Raw-barrier pipeline: global loads stay in flight across s_barrier;
// only lgkmcnt (ds_writes) drained per phase.
__global__ __launch_bounds__(512, 4) void qcdot_k(const float* __restrict__ src,
                                                  const f16* __restrict__ feath,
                                                  const f16* __restrict__ wqh2,
                                                  const float* __restrict__ bq,
                                                  float* __restrict__ dot) {
    __shared__ __align__(16) f16 Bl[2][128 * 64];  // src [px][c-swz], dbuf 2x16KB
    __shared__ __align__(16) f16 Fl[512 * 36];     // feat [(o*2+yi)][36]  36.9KB

    int t = threadIdx.x;
    int bid = blockIdx.x;
    int b = bid >> 7;
    int hp = (bid >> 1) & 63;
    int wh = bid & 1;
    int h = hp * 2;
    int w0 = wh * 64;
    int x0 = wh * 32;
    int ybase = hp;

    // ---- prologue: issue kk=0 src loads ----
    const float* srcb = src + (size_t)b * CC * NPIX + h * WW + w0;
    int q4 = t & 15, rh_t = (t >> 4) & 1, c4 = t >> 5;
    const float* sp0 = srcb + (size_t)(c4 * 4) * NPIX + rh_t * WW + q4 * 4;
    float4 rr[4];
#pragma unroll
    for (int r = 0; r < 4; ++r) rr[r] = *(const float4*)(sp0 + (size_t)r * NPIX);

    // ---- stage feat tile: Fl[(o*2+yi)*36 + xi] ----
    {
        const f16* fb = feath + (size_t)b * CC * DD;
        int o = t >> 1, yi = t & 1;
        int y = ybase + yi;
        const f16* frow = fb + (size_t)o * DD + y * 64 + x0;
        f16* dst = &Fl[(o * 2 + yi) * 36];
        if (y < 64) {
#pragma unroll
            for (int k2 = 0; k2 < 8; ++k2)
                *(f16x4*)&dst[k2 * 4] = *(const f16x4*)&frow[k2 * 4];
            dst[32] = (x0 + 32 < 64) ? frow[32] : (f16)0.f;
        } else {
            f16x4 z = {0, 0, 0, 0};
#pragma unroll
            for (int k2 = 0; k2 < 8; ++k2) *(f16x4*)&dst[k2 * 4] = z;
            dst[32] = (f16)0.f;
        }
    }

    int wv = t >> 6;
    int lane = t & 63;
    int g = lane >> 4;
    int col = lane & 15;
    int rh = wv >> 2;
    int o0 = (wv & 3) * 64;

    f32x4 acc[4][4];
#pragma unroll
    for (int mf = 0; mf < 4; ++mf)
#pragma unroll
        for (int nf = 0; nf < 4; ++nf) acc[mf][nf] = (f32x4){0.f, 0.f, 0.f, 0.f};

    int Gw = c4 >> 1, ho = (c4 & 1) << 2;

#pragma unroll
    for (int kk = 0; kk < 4; ++kk) {
        // (b) cvt + ds_write current src regs -> Bl[kk&1]
#pragma unroll
        for (int p = 0; p < 4; ++p) {
            int px = rh_t * 64 + q4 * 4 + p;
            f16x4 hv = {(f16)(&rr[0].x)[p], (f16)(&rr[1].x)[p],
                        (f16)(&rr[2].x)[p], (f16)(&rr[3].x)[p]};
            *(f16x4*)&Bl[kk & 1][px * 64 + ((Gw ^ (px & 7)) << 3) + ho] = hv;
        }
        // (c) issue next-kk src loads (in-place reuse) + s=0 Wq frags
        if (kk < 3) {
            const float* spn = srcb + (size_t)((kk + 1) * 64 + c4 * 4) * NPIX + rh_t * WW + q4 * 4;
#pragma unroll
            for (int r = 0; r < 4; ++r) rr[r] = *(const float4*)(spn + (size_t)r * NPIX);
        }
        f16x8 bf[4];
#pragma unroll
        for (int nf = 0; nf < 4; ++nf) {
            int o = o0 + nf * 16 + col;
            bf[nf] = *(const f16x8*)&wqh2[(size_t)(((kk * 8 + g) * 256) + o) * 8];
        }
        // (d) raw barrier: drain LDS writes only; global loads stay in flight
        __builtin_amdgcn_sched_barrier(0);
        asm volatile("s_waitcnt lgkmcnt(0)" ::: "memory");
        __builtin_amdgcn_s_barrier();
        __builtin_amdgcn_sched_barrier(0);
        // (e) MFMA: s=0 with preloaded bf, then reload bf for s=1
#pragma unroll
        for (int mf = 0; mf < 4; ++mf) {
            int px = rh * 64 + mf * 16 + col;
            f16x8 af = *(const f16x8*)&Bl[kk & 1][px * 64 + ((g ^ (px & 7)) << 3)];
#pragma unroll
            for (int nf = 0; nf < 4; ++nf)
                acc[mf][nf] = __builtin_amdgcn_mfma_f32_16x16x32_f16(af, bf[nf], acc[mf][nf], 0, 0, 0);
        }
#pragma unroll
        for (int nf = 0; nf < 4; ++nf) {
            int o = o0 + nf * 16 + col;
            bf[nf] = *(const f16x8*)&wqh2[(size_t)(((kk * 8 + 4 + g) * 256) + o) * 8];
        }
#pragma unroll
        for (int mf = 0; mf < 4; ++mf) {
            int px = rh * 64 + mf * 16 + col;
            int G2 = 4 + g;
            f16x8 af = *(const f16x8*)&Bl[kk & 1][px * 64 + ((G2 ^ (px & 7)) << 3)];
#pragma unroll
            for (int nf = 0; nf < 4; ++nf)
                acc[mf][nf] = __builtin_amdgcn_mfma_f32_16x16x32_f16(af, bf[nf], acc[mf][nf], 0, 0, 0);
        }
    }

    // ---- epilogue ----
    int i0 = rh ? 2 : 1;
    float bqv[4];
#pragma unroll
    for (int nf = 0; nf < 4; ++nf) bqv[nf] = bq[o0 + nf * 16 + col];

    float bins[4][2][3];
#pragma unroll
    for (int nf = 0; nf < 4; ++nf)
#pragma unroll
        for (int ii = 0; ii < 2; ++ii)
#pragma unroll
            for (int j = 0; j < 3; ++j) bins[nf][ii][j] = 0.f;

#pragma unroll
    for (int mf = 0; mf < 4; ++mf) {
        int X = mf * 8 + g * 2;
#pragma unroll
        for (int ii = 0; ii < 2; ++ii) {
            if (ii == 1 && rh == 0) continue;   // wave-uniform skip
#pragma unroll
            for (int nf = 0; nf < 4; ++nf) {
                int o = o0 + nf * 16 + col;
                const f16* fr = &Fl[(o * 2 + ii) * 36];
                f16x2 lh = *(const f16x2*)&fr[X];
                float lo = (float)lh[0], hi = (float)lh[1];
                float s2 = (float)fr[X + 2];
                float qv0 = acc[mf][nf][0] + bqv[nf];
                float qv1 = acc[mf][nf][1] + bqv[nf];
                float qv2 = acc[mf][nf][2] + bqv[nf];
                float qv3 = acc[mf][nf][3] + bqv[nf];
                bins[nf][ii][1] += qv0 * lo + qv2 * hi;   // j=1 (even w)
                bins[nf][ii][2] += qv1 * lo + qv3 * hi;   // j=2 (odd w, left)
                bins[nf][ii][0] += qv1 * hi + qv3 * s2;   // j=0 (odd w, right)
            }
        }
    }

#pragma unroll
    for (int m = 16; m <= 32; m <<= 1)
#pragma unroll
        for (int nf = 0; nf < 4; ++nf)
#pragma unroll
            for (int ii = 0; ii < 2; ++ii) {
                if (ii == 1 && rh == 0) continue;
#pragma unroll
                for (int j = 0; j < 3; ++j)
                    bins[nf][ii][j] += __shfl_xor(bins[nf][ii][j], m, 64);
            }

    if (g == 0) {
#pragma unroll
        for (int nf = 0; nf < 4; ++nf) {
            int o = o0 + nf * 16 + col;
            float* dpo = dot + ((size_t)b * CC + o) * 9;
            atomicAdd(dpo + i0 * 3 + 0, bins[nf][0][0]);
            atomicAdd(dpo + i0 * 3 + 1, bins[nf][0][1]);
            atomicAdd(dpo + i0 * 3 + 2, bins[nf][0][2]);
            if (rh) {
                atomicAdd(dpo + 0, bins[nf][1][0]);
                atomicAdd(dpo + 1, bins[nf][1][1]);
                atomicAdd(dpo + 2, bins[nf][1][2]);
            }
        }
    }
}

// v = Wv@feat + bv (f16 MFMA) -> vh (f16). Block: 128 o x 128 d, waves 2x2.
__global__ __launch_bounds__(256) void vc_k(const float* __restrict__ feat,
                                            const float* __restrict__ Wv,
                                            const float* __restrict__ bv,
                                            f16* __restrict__ vh) {
    __shared__ __align__(16) f16 Al[128 * 64];
    __shared__ __align__(16) f16 Bl[128 * 64];
    int t = threadIdx.x;
    int bid = blockIdx.x;
    int b = bid >> 6;
    int rest = bid & 63;
    int o0 = (rest >> 5) * 128;
    int d0 = (rest & 31) * 128;

    int wv = t >> 6;
    int wm = wv >> 1, wn = wv & 1;
    int lane = t & 63;
    int g = lane >> 4;
    int col = lane & 15;

    f32x4 acc[4][4];
#pragma unroll
    for (int mf = 0; mf < 4; ++mf)
#pragma unroll
        for (int nf = 0; nf < 4; ++nf) acc[mf][nf] = (f32x4){0.f, 0.f, 0.f, 0.f};

    const float* featb = feat + (size_t)b * CC * DD + d0;

    for (int kk = 0; kk < 4; ++kk) {
        int c0 = kk * 64;
        {
            int orow = t >> 2;
            int cb = (t & 3) << 4;
#pragma unroll
            for (int oo = 0; oo < 2; ++oo) {
                int o = oo * 64 + orow;
                const float* wr = Wv + (size_t)(o0 + o) * CC + c0 + cb;
                float4 f0 = *(const float4*)(wr);
                float4 f1 = *(const float4*)(wr + 4);
                float4 f2 = *(const float4*)(wr + 8);
                float4 f3 = *(const float4*)(wr + 12);
                f16x8 h0 = {(f16)f0.x, (f16)f0.y, (f16)f0.z, (f16)f0.w,
                            (f16)f1.x, (f16)f1.y, (f16)f1.z, (f16)f1.w};
                f16x8 h1 = {(f16)f2.x, (f16)f2.y, (f16)f2.z, (f16)f2.w,
                            (f16)f3.x, (f16)f3.y, (f16)f3.z, (f16)f3.w};
                int Gb = cb >> 3;
                *(f16x8*)&Al[o * 64 + ((Gb ^ (o & 7)) << 3)] = h0;
                *(f16x8*)&Al[o * 64 + (((Gb + 1) ^ (o & 7)) << 3)] = h1;
            }
        }
        {
            int q4b = t & 31;
            int oc = t >> 5;
            const float* fp = featb + (size_t)(c0 + oc * 8) * DD + q4b * 4;
            float4 rr[8];
#pragma unroll
            for (int r = 0; r < 8; ++r) rr[r] = *(const float4*)(fp + (size_t)r * DD);
#pragma unroll
            for (int p = 0; p < 4; ++p) {
                int d = q4b * 4 + p;
                f16x8 hv = {(f16)(&rr[0].x)[p], (f16)(&rr[1].x)[p], (f16)(&rr[2].x)[p],
                            (f16)(&rr[3].x)[p], (f16)(&rr[4].x)[p], (f16)(&rr[5].x)[p],
                            (f16)(&rr[6].x)[p], (f16)(&rr[7].x)[p]};
                *(f16x8*)&Bl[d * 64 + ((oc ^ (d & 7)) << 3)] = hv;
            }
        }
        __syncthreads();
#pragma unroll
        for (int s = 0; s < 2; ++s) {
            f16x8 af[4], bf[4];
            int G = s * 4 + g;
#pragma unroll
            for (int mf = 0; mf < 4; ++mf) {
                int orow = wm * 64 + mf * 16 + col;
                af[mf] = *(const f16x8*)&Al[orow * 64 + ((G ^ (orow & 7)) << 3)];
            }
#pragma unroll
            for (int nf = 0; nf < 4; ++nf) {
                int drow = wn * 64 + nf * 16 + col;
                bf[nf] = *(const f16x8*)&Bl[drow * 64 + ((G ^ (drow & 7)) << 3)];
            }
#pragma unroll
            for (int mf = 0; mf < 4; ++mf)
#pragma unroll
                for (int nf = 0; nf < 4; ++nf)
                    acc[mf][nf] = __builtin_amdgcn_mfma_f32_16x16x32_f16(af[mf], bf[nf], acc[mf][nf], 0, 0, 0);
        }
        __syncthreads();
    }

    f16* vb = vh + ((size_t)b * CC + o0) * DD + d0;
#pragma unroll
    for (int mf = 0; mf < 4; ++mf)
#pragma unroll
        for (int nf = 0; nf < 4; ++nf) {
#pragma unroll
            for (int r = 0; r < 4; ++r) {
                int o = wm * 64 + mf * 16 + g * 4 + r;
                int d = wn * 64 + nf * 16 + col;
                vb[(size_t)o * DD + d] = (f16)(acc[mf][nf][r] + bv[o0 + o]);
            }
        }
}

__global__ void sm_k(const float* __restrict__ dot, float* __restrict__ A) {
    int i = blockIdx.x * 256 + threadIdx.x;
    if (i >= BB * CC) return;
    float s[9];
    float m = -1e30f;
    const float sc = 1.f / 64.f;
#pragma unroll
    for (int k = 0; k < 9; ++k) { s[k] = dot[(size_t)i * 9 + k] * sc; m = fmaxf(m, s[k]); }
    float sum = 0.f;
#pragma unroll
    for (int k = 0; k < 9; ++k) { s[k] = __expf(s[k] - m); sum += s[k]; }
    float inv = 1.f / sum;
#pragma unroll
    for (int k = 0; k < 9; ++k) A[(size_t)i * 9 + k] = s[k] * inv;
}

// out: each thread computes 4 consecutive w via float4.
// Block = (bc, h-octet): 256 thr = 8 h x 32 w-groups.
__global__ __launch_bounds__(256) void out_k(const float* __restrict__ src,
                                             const f16* __restrict__ vh,
                                             const float* __restrict__ A,
                                             float* __restrict__ out) {
    __shared__ float Al[9];
    int bid = blockIdx.x;
    int bc = bid >> 4;
    int h0 = (bid & 15) << 3;
    int t = threadIdx.x;
    if (t < 9) Al[t] = A[(size_t)bc * 9 + t];
    __syncthreads();
    int h = h0 + (t >> 5);
    int a = t & 31;              // w = 4a..4a+3
    bool hodd = (h & 1) != 0;
    // term A: always present. even h: i=1,y=h/2. odd h: i=2,y=(h-1)/2.
    int iA = hodd ? 2 : 1;
    int yA = hodd ? ((h - 1) >> 1) : (h >> 1);
    // term B: odd h only, i=0, y=(h+1)/2 (valid while <64)
    int yB = (h + 1) >> 1;
    bool hasB = hodd && (yB < 64);

    const f16* vb = vh + (size_t)bc * DD;
    float s0 = 0.f, s1 = 0.f, s2 = 0.f, s3 = 0.f;
    {
        const f16* vr = vb + yA * OWW + 2 * a;
        f16x2 v01 = *(const f16x2*)vr;
        float V0 = (float)v01[0], V1 = (float)v01[1];
        float V2 = (2 * a + 2 < 64) ? (float)vr[2] : 0.f;
        float A0 = Al[iA * 3 + 0], A1 = Al[iA * 3 + 1], A2 = Al[iA * 3 + 2];
        s0 += A1 * V0;
        s1 += A0 * V1 + A2 * V0;
        s2 += A1 * V1;
        s3 += A0 * V2 + A2 * V1;
    }
    if (hasB) {
        const f16* vr = vb + yB * OWW + 2 * a;
        f16x2 v01 = *(const f16x2*)vr;
        float V0 = (float)v01[0], V1 = (float)v01[1];
        float V2 = (2 * a + 2 < 64) ? (float)vr[2] : 0.f;
        float A0 = Al[0], A1 = Al[1], A2 = Al[2];
        s0 += A1 * V0;
        s1 += A0 * V1 + A2 * V0;
        s2 += A1 * V1;
        s3 += A0 * V2 + A2 * V1;
    }
    size_t idx = (size_t)bc * NPIX + (size_t)h * WW + a * 4;
    float4 sv = *(const float4*)(src + idx);
    float4 o4;
    o4.x = s0 * sv.x; o4.y = s1 * sv.y; o4.z = s2 * sv.z; o4.w = s3 * sv.w;
    *(float4*)(out + idx) = o4;
}

extern "C" void kernel_launch(void* const* d_in, const int* in_sizes, int n_in,
                              void* d_out, int out_size, void* d_ws, size_t ws_size,
                              hipStream_t stream) {
    const float* feat = (const float*)d_in[0];
    const float* src  = (const float*)d_in[1];
    const float* Wq   = (const float*)d_in[2];
    const float* bq   = (const float*)d_in[3];
    const float* Wv   = (const float*)d_in[4];
    const float* bv   = (const float*)d_in[5];
    float* out = (float*)d_out;

    f16*  vh    = (f16*)d_ws;                               // 4*256*4096 f16
    float* dotb = (float*)(vh + (size_t)BB * CC * DD);      // 9216 f32
    float* A    = dotb + (size_t)BB * CC * 9;               // 9216 f32
    f16*  feath = (f16*)(A + (size_t)BB * CC * 9);          // 4*256*4096 f16
    f16*  wqh2  = feath + (size_t)BB * CC * DD + 64;        // 65536 f16

    zero_k<<<(BB * CC * 9 + 255) / 256, 256, 0, stream>>>(dotb, BB * CC * 9);
    prep_feat_k<<<BB * CC * DD / 2048, 256, 0, stream>>>(feat, feath);
    prep_wq_k<<<8, 256, 0, stream>>>(Wq, wqh2);
    qcdot_k<<<BB * 64 * 2, 512, 0, stream>>>(src, feath, wqh2, bq, dotb);
    vc_k<<<BB * 64, 256, 0, stream>>>(feat, Wv, bv, vh);
    sm_k<<<(BB * CC + 255) / 256, 256, 0, stream>>>(dotb, A);
    out_k<<<BB * CC * 16, 256, 0, stream>>>(src, vh, A, out);
}